// Round 5
// baseline (117.773 us; speedup 1.0000x reference)
//
#include <hip/hip_runtime.h>

// LSH attention (Reformer-style) on MI355X.
// out0 == v exactly -> fused float4 copy.
// out1 = buckets via MFMA: fp32 split into bf16 hi+lo (RNE), dots =
// hi*hi + hi*lo + lo*hi on v_mfma_f32_16x16x32_bf16 (err <= ~1e-3).
// Certified top-2 argmax with MARGIN=8e-3; small-gap rows repaired in
// fp64 (sequential-f, bitwise-identical to the R1-R4 passing path).
// Layouts (HW-verified per guide): A[m=lane&15][k=quad*8+j], B symmetric,
// C/D col=lane&15, row=quad*4+reg.

namespace {
constexpr int S_LEN   = 8192;
constexpr int D_DIM   = 64;
constexpr int N_HASH  = 8;
constexpr int N_BUCK  = 128;
constexpr int T_TILE  = 128;   // t rows per block (4 waves x 32 rows)
constexpr int THREADS = 256;
constexpr int BATCH   = 4;
constexpr float MARGIN = 8e-3f;  // >= 4x the bf16-split GEMM error bound
constexpr long long OUT0_ELEMS = (long long)BATCH * S_LEN * D_DIM;
}

typedef __attribute__((ext_vector_type(8))) short bf16x8;
typedef __attribute__((ext_vector_type(4))) float f32x4;

__device__ __forceinline__ unsigned short f2bf(float x) {
  unsigned u = __float_as_uint(x);
  return (unsigned short)((u + 0x7fffu + ((u >> 16) & 1u)) >> 16);  // RNE
}
__device__ __forceinline__ float bf2f(unsigned short h) {
  return __uint_as_float(((unsigned)h) << 16);
}

__global__ __launch_bounds__(THREADS, 4) void lsh_mfma_kernel(
    const float* __restrict__ qk, const float* __restrict__ v,
    const float* __restrict__ rot, float* __restrict__ out) {
  const int b    = blockIdx.z;
  const int h    = blockIdx.y;
  const int tile = blockIdx.x;
  const int tid  = threadIdx.x;
  const int wave = tid >> 6;
  const int lane = tid & 63;
  const int col  = lane & 15;   // MFMA n / m index
  const int quad = lane >> 4;   // MFMA k-group / C-row group

  __shared__ int s_cnt;
  __shared__ int s_list[T_TILE];
  if (tid == 0) s_cnt = 0;

  // ---- fused out0 = v copy: 2048 blocks x 256 threads x 1 float4 ----
  {
    const int bid = blockIdx.x + gridDim.x * (blockIdx.y + gridDim.y * blockIdx.z);
    ((float4*)out)[bid * THREADS + tid] = ((const float4*)v)[bid * THREADS + tid];
  }
  __syncthreads();  // s_cnt init visible before any epilogue atomicAdd

  // ---- B fragments (rot slice for this h), hi/lo bf16, built per wave ----
  // B element: k = kk*32 + quad*8 + j, n = nt*16 + col.
  // rot layout: [f][h][i] with f-stride 512. 128 KB total -> L2-resident.
  bf16x8 Bh[4][2], Bl[4][2];
  {
    const float* rp = rot + h * 64;
#pragma unroll
    for (int nt = 0; nt < 4; ++nt) {
      const int n = nt * 16 + col;
#pragma unroll
      for (int kk = 0; kk < 2; ++kk) {
#pragma unroll
        for (int j = 0; j < 8; ++j) {
          const float x = rp[(size_t)(kk * 32 + quad * 8 + j) * 512 + n];
          const unsigned short hb = f2bf(x);
          Bh[nt][kk][j] = (short)hb;
          Bl[nt][kk][j] = (short)f2bf(x - bf2f(hb));
        }
      }
    }
  }

  const int trow0 = tile * T_TILE + wave * 32;
  const int h_off = h * N_BUCK;
  float* outb = out + OUT0_ELEMS + ((size_t)b * N_HASH + h) * S_LEN + tile * T_TILE;

#pragma unroll
  for (int mt = 0; mt < 2; ++mt) {
    // ---- A fragments: q rows, m = col, k = kk*32 + quad*8 + j ----
    const float* qrow = qk + ((size_t)b * S_LEN + trow0 + mt * 16 + col) * D_DIM;
    bf16x8 Ah[2], Al[2];
#pragma unroll
    for (int kk = 0; kk < 2; ++kk) {
      float qb[8];
      *(float4*)qb       = *(const float4*)(qrow + kk * 32 + quad * 8);
      *(float4*)(qb + 4) = *(const float4*)(qrow + kk * 32 + quad * 8 + 4);
#pragma unroll
      for (int j = 0; j < 8; ++j) {
        const unsigned short hb = f2bf(qb[j]);
        Ah[kk][j] = (short)hb;
        Al[kk][j] = (short)f2bf(qb[j] - bf2f(hb));
      }
    }

    // ---- 3-product split GEMM: C = Ah*Bh + Ah*Bl + Al*Bh ----
    f32x4 acc[4];
#pragma unroll
    for (int nt = 0; nt < 4; ++nt) {
      f32x4 c = {0.f, 0.f, 0.f, 0.f};
#pragma unroll
      for (int kk = 0; kk < 2; ++kk) {
        c = __builtin_amdgcn_mfma_f32_16x16x32_bf16(Ah[kk], Bh[nt][kk], c, 0, 0, 0);
        c = __builtin_amdgcn_mfma_f32_16x16x32_bf16(Ah[kk], Bl[nt][kk], c, 0, 0, 0);
        c = __builtin_amdgcn_mfma_f32_16x16x32_bf16(Al[kk], Bh[nt][kk], c, 0, 0, 0);
      }
      acc[nt] = c;
    }

    // ---- epilogue: per C-row certified top-2 argmax over 128 = [r, -r] ----
    // C layout: value for row (quad*4+reg) at i = nt*16 + col.
#pragma unroll
    for (int reg = 0; reg < 4; ++reg) {
      float v1 = -3e38f, v2 = -3e38f;
      int i1 = 0;
#pragma unroll
      for (int nt = 0; nt < 4; ++nt) {
        const float val = acc[nt][reg];
        const int ip = nt * 16 + col;
        if (val > v1 || (val == v1 && ip < i1)) { v2 = v1; v1 = val; i1 = ip; }
        else if (val > v2) { v2 = val; }
        const float nv = -val;
        const int in_ = 64 + ip;
        if (nv > v1 || (nv == v1 && in_ < i1)) { v2 = v1; v1 = nv; i1 = in_; }
        else if (nv > v2) { v2 = nv; }
      }
      // butterfly across the 16 lanes of this quad
#pragma unroll
      for (int m = 1; m < 16; m <<= 1) {
        const float ov1 = __shfl_xor(v1, m);
        const int   oi1 = __shfl_xor(i1, m);
        const float ov2 = __shfl_xor(v2, m);
        if (ov1 > v1 || (ov1 == v1 && oi1 < i1)) {
          v2 = fmaxf(v1, ov2); v1 = ov1; i1 = oi1;
        } else {
          v2 = fmaxf(v2, ov1);
        }
      }
      if (col == 0) {
        const int t_local = wave * 32 + mt * 16 + quad * 4 + reg;
        if (v1 - v2 < MARGIN) {
          s_list[atomicAdd(&s_cnt, 1)] = t_local;   // rare: certify in fp64
        } else {
          outb[t_local] = (float)(i1 + h_off);
        }
      }
    }
  }

  __syncthreads();

  // ---- rare fp64 repair: one wave per flagged row, lane = column i ----
  const int cnt = s_cnt;
  for (int it = wave; it < cnt; it += THREADS / 64) {
    const int tl = s_list[it];
    const float* qrow = qk + ((size_t)b * S_LEN + tile * T_TILE + tl) * D_DIM;
    double dot = 0.0;
#pragma unroll 8
    for (int f = 0; f < D_DIM; ++f)
      dot = fma((double)qrow[f], (double)rot[(size_t)f * 512 + h * 64 + lane], dot);
    double vp = dot, vn = -dot;
    int ip = lane, in_ = 64 + lane;
#pragma unroll
    for (int m = 1; m < 64; m <<= 1) {
      const double ovp = __shfl_xor(vp, m);
      const int   oip = __shfl_xor(ip, m);
      if (ovp > vp || (ovp == vp && oip < ip)) { vp = ovp; ip = oip; }
      const double ovn = __shfl_xor(vn, m);
      const int   oin = __shfl_xor(in_, m);
      if (ovn > vn || (ovn == vn && oin < in_)) { vn = ovn; in_ = oin; }
    }
    if (lane == 0) {
      const int bucket = (vp >= vn) ? ip : in_;
      outb[tl] = (float)(bucket + h_off);
    }
  }
}

extern "C" void kernel_launch(void* const* d_in, const int* in_sizes, int n_in,
                              void* d_out, int out_size, void* d_ws, size_t ws_size,
                              hipStream_t stream) {
  const float* qk  = (const float*)d_in[0];
  const float* v   = (const float*)d_in[1];
  const float* rot = (const float*)d_in[2];
  float* out = (float*)d_out;

  dim3 grid(S_LEN / T_TILE, N_HASH, BATCH);
  lsh_mfma_kernel<<<grid, THREADS, 0, stream>>>(qk, v, rot, out);
}

// Round 6
// 99.680 us; speedup vs baseline: 1.1815x; 1.1815x over previous
//
#include <hip/hip_runtime.h>

// LSH attention (Reformer-style) on MI355X.
// out0 == v exactly -> fused float4 copy.
// out1 = buckets via MFMA: fp32 split into bf16 hi(trunc)+lo, dots =
// Ah*Bh + Ah*Bl + Al*Bh on v_mfma_f32_16x16x32_bf16 (err <= ~1e-3).
// Certified top-2 argmax (MARGIN=8e-3); small-gap rows repaired in fp64.
// R6: rot pre-split to bf16 hi/lo in LDS (72-short stride: conflict-free
// b128 frag reads); hoist Bh only (32 VGPR), stream Bl from LDS.
// R5's resident Bh+Bl+build (64+ regs) spilled: WRITE_SIZE 84 MB.

namespace {
constexpr int S_LEN   = 8192;
constexpr int D_DIM   = 64;
constexpr int N_HASH  = 8;
constexpr int N_BUCK  = 128;
constexpr int T_TILE  = 128;   // rows per block: 4 waves x 2 mt x 16
constexpr int THREADS = 256;
constexpr int BATCH   = 4;
constexpr int BSTRIDE = 72;    // LDS shorts per n-row (64 + 8 pad)
constexpr float MARGIN = 8e-3f;
constexpr long long OUT0_ELEMS = (long long)BATCH * S_LEN * D_DIM;
}

typedef __attribute__((ext_vector_type(8))) short bf16x8;
typedef __attribute__((ext_vector_type(4))) float f32x4;

__device__ __forceinline__ void split_bf16(float x, short& hi, short& lo) {
  const unsigned u = __float_as_uint(x);
  hi = (short)(u >> 16);                                  // truncation
  const float l = x - __uint_as_float(u & 0xFFFF0000u);   // exact remainder
  lo = (short)(__float_as_uint(l) >> 16);                 // |err| <= 2^-16|x|
}

__global__ __launch_bounds__(THREADS, 4) void lsh_mfma_kernel(
    const float* __restrict__ qk, const float* __restrict__ v,
    const float* __restrict__ rot, float* __restrict__ out) {
  const int b    = blockIdx.z;
  const int h    = blockIdx.y;
  const int tile = blockIdx.x;
  const int tid  = threadIdx.x;
  const int wave = tid >> 6;
  const int lane = tid & 63;
  const int col  = lane & 15;   // MFMA m / n index
  const int quad = lane >> 4;   // MFMA k-group / C-row group

  __shared__ __align__(16) unsigned short lbh[64 * BSTRIDE];  // B hi [n][k]
  __shared__ __align__(16) unsigned short lbl[64 * BSTRIDE];  // B lo [n][k]
  __shared__ int s_cnt;
  __shared__ int s_list[T_TILE];
  if (tid == 0) s_cnt = 0;

  // ---- fused out0 = v copy: 2048 blocks x 256 threads x 1 float4 ----
  {
    const int bid = blockIdx.x + gridDim.x * (blockIdx.y + gridDim.y * blockIdx.z);
    ((float4*)out)[bid * THREADS + tid] = ((const float4*)v)[bid * THREADS + tid];
  }

  // ---- stage rot[.,h,.] -> LDS, pre-split hi/lo bf16, k-contiguous ----
  // thread: n = tid>>2, k0 = (tid&3)*16; 16 strided f32 loads (L2-hot),
  // two ds_write_b128 per array.
  {
    const int n  = tid >> 2;
    const int k0 = (tid & 3) * 16;
    const float* rp = rot + h * 64 + n;
    short hs[16], ls[16];
#pragma unroll
    for (int j = 0; j < 16; ++j)
      split_bf16(rp[(size_t)(k0 + j) * 512], hs[j], ls[j]);
    *(bf16x8*)&lbh[n * BSTRIDE + k0]     = *(bf16x8*)hs;
    *(bf16x8*)&lbh[n * BSTRIDE + k0 + 8] = *(bf16x8*)(hs + 8);
    *(bf16x8*)&lbl[n * BSTRIDE + k0]     = *(bf16x8*)ls;
    *(bf16x8*)&lbl[n * BSTRIDE + k0 + 8] = *(bf16x8*)(ls + 8);
  }
  __syncthreads();

  // ---- hoist Bh fragments (32 VGPR); Bl streamed at use ----
  bf16x8 Bh[4][2];
#pragma unroll
  for (int nt = 0; nt < 4; ++nt)
#pragma unroll
    for (int kk = 0; kk < 2; ++kk)
      Bh[nt][kk] = *(const bf16x8*)&lbh[(nt * 16 + col) * BSTRIDE + kk * 32 + quad * 8];

  const int trow0 = tile * T_TILE + wave * 32;
  const int h_off = h * N_BUCK;
  float* outb = out + OUT0_ELEMS + ((size_t)b * N_HASH + h) * S_LEN + tile * T_TILE;

#pragma unroll
  for (int mt = 0; mt < 2; ++mt) {
    // ---- A fragments: q row (m=col), k = kk*32 + quad*8 + j ----
    const float* qrow = qk + ((size_t)b * S_LEN + trow0 + mt * 16 + col) * D_DIM;
    bf16x8 Ah[2], Al[2];
#pragma unroll
    for (int kk = 0; kk < 2; ++kk) {
      float qb[8];
      *(float4*)qb       = *(const float4*)(qrow + kk * 32 + quad * 8);
      *(float4*)(qb + 4) = *(const float4*)(qrow + kk * 32 + quad * 8 + 4);
      short hs[8], ls[8];
#pragma unroll
      for (int j = 0; j < 8; ++j) split_bf16(qb[j], hs[j], ls[j]);
      Ah[kk] = *(bf16x8*)hs;
      Al[kk] = *(bf16x8*)ls;
    }

    // ---- split GEMM: C = Ah*Bh + Ah*Bl + Al*Bh ----
    f32x4 acc[4];
#pragma unroll
    for (int nt = 0; nt < 4; ++nt) {
      f32x4 c = {0.f, 0.f, 0.f, 0.f};
#pragma unroll
      for (int kk = 0; kk < 2; ++kk) {
        const bf16x8 bl =
            *(const bf16x8*)&lbl[(nt * 16 + col) * BSTRIDE + kk * 32 + quad * 8];
        c = __builtin_amdgcn_mfma_f32_16x16x32_bf16(Ah[kk], Bh[nt][kk], c, 0, 0, 0);
        c = __builtin_amdgcn_mfma_f32_16x16x32_bf16(Ah[kk], bl, c, 0, 0, 0);
        c = __builtin_amdgcn_mfma_f32_16x16x32_bf16(Al[kk], Bh[nt][kk], c, 0, 0, 0);
      }
      acc[nt] = c;
    }

    // ---- epilogue: per C-row certified top-2 argmax over 128 = [r, -r] ----
#pragma unroll
    for (int reg = 0; reg < 4; ++reg) {
      float v1 = -3e38f, v2 = -3e38f;
      int i1 = 0;
#pragma unroll
      for (int nt = 0; nt < 4; ++nt) {
        const float val = acc[nt][reg];
        const int ip = nt * 16 + col;
        if (val > v1 || (val == v1 && ip < i1)) { v2 = v1; v1 = val; i1 = ip; }
        else if (val > v2) { v2 = val; }
        const float nv = -val;
        const int in_ = 64 + ip;
        if (nv > v1 || (nv == v1 && in_ < i1)) { v2 = v1; v1 = nv; i1 = in_; }
        else if (nv > v2) { v2 = nv; }
      }
#pragma unroll
      for (int m = 1; m < 16; m <<= 1) {
        const float ov1 = __shfl_xor(v1, m);
        const int   oi1 = __shfl_xor(i1, m);
        const float ov2 = __shfl_xor(v2, m);
        if (ov1 > v1 || (ov1 == v1 && oi1 < i1)) {
          v2 = fmaxf(v1, ov2); v1 = ov1; i1 = oi1;
        } else {
          v2 = fmaxf(v2, ov1);
        }
      }
      if (col == 0) {
        const int t_local = wave * 32 + mt * 16 + quad * 4 + reg;
        if (v1 - v2 < MARGIN) {
          s_list[atomicAdd(&s_cnt, 1)] = t_local;   // rare: certify in fp64
        } else {
          outb[t_local] = (float)(i1 + h_off);
        }
      }
    }
  }

  __syncthreads();

  // ---- rare fp64 repair: one wave per flagged row, lane = column i ----
  const int cnt = s_cnt;
  for (int it = wave; it < cnt; it += THREADS / 64) {
    const int tl = s_list[it];
    const float* qrow = qk + ((size_t)b * S_LEN + tile * T_TILE + tl) * D_DIM;
    double dot = 0.0;
#pragma unroll 8
    for (int f = 0; f < D_DIM; ++f)
      dot = fma((double)qrow[f], (double)rot[(size_t)f * 512 + h * 64 + lane], dot);
    double vp = dot, vn = -dot;
    int ip = lane, in_ = 64 + lane;
#pragma unroll
    for (int m = 1; m < 64; m <<= 1) {
      const double ovp = __shfl_xor(vp, m);
      const int   oip = __shfl_xor(ip, m);
      if (ovp > vp || (ovp == vp && oip < ip)) { vp = ovp; ip = oip; }
      const double ovn = __shfl_xor(vn, m);
      const int   oin = __shfl_xor(in_, m);
      if (ovn > vn || (ovn == vn && oin < in_)) { vn = ovn; in_ = oin; }
    }
    if (lane == 0) {
      const int bucket = (vp >= vn) ? ip : in_;
      outb[tl] = (float)(bucket + h_off);
    }
  }
}

extern "C" void kernel_launch(void* const* d_in, const int* in_sizes, int n_in,
                              void* d_out, int out_size, void* d_ws, size_t ws_size,
                              hipStream_t stream) {
  const float* qk  = (const float*)d_in[0];
  const float* v   = (const float*)d_in[1];
  const float* rot = (const float*)d_in[2];
  float* out = (float*)d_out;

  dim3 grid(S_LEN / T_TILE, N_HASH, BATCH);
  lsh_mfma_kernel<<<grid, THREADS, 0, stream>>>(qk, v, rot, out);
}

// Round 7
// 84.795 us; speedup vs baseline: 1.3889x; 1.1755x over previous
//
#include <hip/hip_runtime.h>

// LSH attention (Reformer-style) on MI355X.
// out0 == v exactly -> fused float4 copy.
// out1 = buckets via MFMA bf16 hi/lo split (3 products, err <= ~1e-3),
// certified packed-key argmax (MARGIN=8e-3 >= 3x total error bound);
// ambiguous rows repaired in fp64 (proven bit-exact path, R1-R6).
// R7: 2 h per block -> grid 1024 = 4 blocks/CU fully resident (no
// residency tail), A-frags split once for both h; epilogue rebuilt on
// u32 packed keys (|v| high-bits | 127-concat_idx): +/- pair collapse,
// max/min/max3 merges, ties/zeros -> repair. v_perm packs hi/lo pairs.

namespace {
constexpr int S_LEN   = 8192;
constexpr int D_DIM   = 64;
constexpr int N_HASH  = 8;
constexpr int N_BUCK  = 128;
constexpr int T_TILE  = 128;   // rows per block: 4 waves x 2 mt x 16
constexpr int THREADS = 256;
constexpr int BATCH   = 4;
constexpr int H_PER   = 2;     // h values per block
constexpr int BSTRIDE = 72;    // LDS shorts per n-row (64 + 8 pad)
constexpr float MARGIN = 8e-3f;
constexpr long long OUT0_ELEMS = (long long)BATCH * S_LEN * D_DIM;
}

typedef __attribute__((ext_vector_type(8))) short bf16x8;
typedef __attribute__((ext_vector_type(4))) float f32x4;
typedef __attribute__((ext_vector_type(4))) unsigned uint4v;

// dword = [lo16 = hi16(x0) | hi16 = hi16(x1)]  (bf16 truncation pack)
__device__ __forceinline__ unsigned pack_hi16(unsigned u0, unsigned u1) {
  return __builtin_amdgcn_perm(u1, u0, 0x07060302u);
}

__global__ __launch_bounds__(THREADS, 4) void lsh_mfma_kernel(
    const float* __restrict__ qk, const float* __restrict__ v,
    const float* __restrict__ rot, float* __restrict__ out) {
  const int b    = blockIdx.z;
  const int hb   = blockIdx.y;   // h-pair index (h = hb*2 + hh)
  const int tile = blockIdx.x;
  const int tid  = threadIdx.x;
  const int wave = tid >> 6;
  const int lane = tid & 63;
  const int col  = lane & 15;    // MFMA m / n index
  const int quad = lane >> 4;    // MFMA k-group / C-row group

  __shared__ __align__(16) unsigned short lbh[H_PER][64 * BSTRIDE];
  __shared__ __align__(16) unsigned short lbl[H_PER][64 * BSTRIDE];
  __shared__ int s_cnt;
  __shared__ int s_list[H_PER * T_TILE];
  if (tid == 0) s_cnt = 0;

  // ---- fused out0 = v copy: 1024 blocks x 256 threads x 2 float4 ----
  {
    const int bid = blockIdx.x + gridDim.x * (blockIdx.y + gridDim.y * blockIdx.z);
    const int base = bid * 512 + tid;
    ((float4*)out)[base]       = ((const float4*)v)[base];
    ((float4*)out)[base + 256] = ((const float4*)v)[base + 256];
  }

  // ---- stage rot[.,h,.] -> LDS bf16 hi/lo, k-contiguous per n ----
  {
    const int n  = tid >> 2;
    const int k0 = (tid & 3) * 16;
#pragma unroll
    for (int hh = 0; hh < H_PER; ++hh) {
      const float* rp = rot + (hb * H_PER + hh) * 64 + n;
      unsigned hu[8], lu[8];
#pragma unroll
      for (int p = 0; p < 8; ++p) {
        const float x0 = rp[(size_t)(k0 + 2 * p) * 512];
        const float x1 = rp[(size_t)(k0 + 2 * p + 1) * 512];
        const unsigned u0 = __float_as_uint(x0);
        const unsigned u1 = __float_as_uint(x1);
        const float l0 = x0 - __uint_as_float(u0 & 0xffff0000u);
        const float l1 = x1 - __uint_as_float(u1 & 0xffff0000u);
        hu[p] = pack_hi16(u0, u1);
        lu[p] = pack_hi16(__float_as_uint(l0), __float_as_uint(l1));
      }
      const int off = n * BSTRIDE + k0;
      *(uint4v*)&lbh[hh][off]     = uint4v{hu[0], hu[1], hu[2], hu[3]};
      *(uint4v*)&lbh[hh][off + 8] = uint4v{hu[4], hu[5], hu[6], hu[7]};
      *(uint4v*)&lbl[hh][off]     = uint4v{lu[0], lu[1], lu[2], lu[3]};
      *(uint4v*)&lbl[hh][off + 8] = uint4v{lu[4], lu[5], lu[6], lu[7]};
    }
  }
  __syncthreads();

  // ---- A fragments for BOTH mt, split once, reused across both h ----
  const int trow0 = tile * T_TILE + wave * 32;
  bf16x8 Ah[2][2], Al[2][2];   // [mt][kk]
#pragma unroll
  for (int mt = 0; mt < 2; ++mt) {
    const float* qrow = qk + ((size_t)b * S_LEN + trow0 + mt * 16 + col) * D_DIM;
#pragma unroll
    for (int kk = 0; kk < 2; ++kk) {
      float qb[8];
      *(float4*)qb       = *(const float4*)(qrow + kk * 32 + quad * 8);
      *(float4*)(qb + 4) = *(const float4*)(qrow + kk * 32 + quad * 8 + 4);
      unsigned hu[4], lu[4];
#pragma unroll
      for (int p = 0; p < 4; ++p) {
        const unsigned u0 = __float_as_uint(qb[2 * p]);
        const unsigned u1 = __float_as_uint(qb[2 * p + 1]);
        const float l0 = qb[2 * p]     - __uint_as_float(u0 & 0xffff0000u);
        const float l1 = qb[2 * p + 1] - __uint_as_float(u1 & 0xffff0000u);
        hu[p] = pack_hi16(u0, u1);
        lu[p] = pack_hi16(__float_as_uint(l0), __float_as_uint(l1));
      }
      Ah[mt][kk] = __builtin_bit_cast(bf16x8, uint4v{hu[0], hu[1], hu[2], hu[3]});
      Al[mt][kk] = __builtin_bit_cast(bf16x8, uint4v{lu[0], lu[1], lu[2], lu[3]});
    }
  }

  const int basec0 = 127 - col;  // key code base: 127 - (nt*16+col) - 64*sign

#pragma unroll
  for (int hh = 0; hh < H_PER; ++hh) {
    const int h = hb * H_PER + hh;
    // hoist Bh fragments (32 VGPR); Bl streamed at use
    bf16x8 Bh[4][2];
#pragma unroll
    for (int nt = 0; nt < 4; ++nt)
#pragma unroll
      for (int kk = 0; kk < 2; ++kk)
        Bh[nt][kk] =
            *(const bf16x8*)&lbh[hh][(nt * 16 + col) * BSTRIDE + kk * 32 + quad * 8];

    float* outb = out + OUT0_ELEMS + ((size_t)(b * N_HASH + h)) * S_LEN + tile * T_TILE;

#pragma unroll
    for (int mt = 0; mt < 2; ++mt) {
      // ---- split GEMM: C = Ah*Bh + Ah*Bl + Al*Bh ----
      f32x4 acc[4];
#pragma unroll
      for (int nt = 0; nt < 4; ++nt) {
        f32x4 c = {0.f, 0.f, 0.f, 0.f};
#pragma unroll
        for (int kk = 0; kk < 2; ++kk) {
          const bf16x8 bl =
              *(const bf16x8*)&lbl[hh][(nt * 16 + col) * BSTRIDE + kk * 32 + quad * 8];
          c = __builtin_amdgcn_mfma_f32_16x16x32_bf16(Ah[mt][kk], Bh[nt][kk], c, 0, 0, 0);
          c = __builtin_amdgcn_mfma_f32_16x16x32_bf16(Ah[mt][kk], bl, c, 0, 0, 0);
          c = __builtin_amdgcn_mfma_f32_16x16x32_bf16(Al[mt][kk], Bh[nt][kk], c, 0, 0, 0);
        }
        acc[nt] = c;
      }

      // ---- packed-key certified top-2 argmax ----
      // key = (|v| & ~0x7F) | code, code = 127 - idx (idx = concat index,
      // +64 if the winning sign is negative). u32-monotone in value, ties
      // pick the smaller idx. -|v| candidates can't reach top-2 unless all
      // zero (-> gap 0 -> repair).
#pragma unroll
      for (int reg = 0; reg < 4; ++reg) {
        unsigned m1 = 0u, m2 = 0u;
#pragma unroll
        for (int nt = 0; nt < 4; ++nt) {
          const unsigned u = __float_as_uint(acc[nt][reg]);
          const unsigned a = u & 0x7fffffffu;
          const unsigned code = (unsigned)(basec0 - nt * 16) - ((u >> 25) & 0x40u);
          const unsigned key = (a & 0xffffff80u) | code;
          const unsigned t = min(m1, key);
          m2 = max(m2, t);
          m1 = max(m1, key);
        }
#pragma unroll
        for (int m = 1; m < 16; m <<= 1) {
          const unsigned o1 = (unsigned)__shfl_xor((int)m1, m);
          const unsigned o2 = (unsigned)__shfl_xor((int)m2, m);
          const unsigned t = min(m1, o1);
          m2 = max(max(m2, o2), t);
          m1 = max(m1, o1);
        }
        if (col == 0) {
          const float v1 = __uint_as_float(m1 & 0xffffff80u);
          const float v2 = __uint_as_float(m2 & 0xffffff80u);
          const int t_local = wave * 32 + mt * 16 + quad * 4 + reg;
          if (v1 - v2 < MARGIN) {
            s_list[atomicAdd(&s_cnt, 1)] = (hh << 8) | t_local;  // rare
          } else {
            const int idx = 127 - (int)(m1 & 0x7fu);
            outb[t_local] = (float)(idx + h * N_BUCK);
          }
        }
      }
    }
  }

  __syncthreads();

  // ---- rare fp64 repair: one wave per flagged row, lane = column i ----
  const int cnt = s_cnt;
  for (int it = wave; it < cnt; it += THREADS / 64) {
    const int e  = s_list[it];
    const int hh = e >> 8;
    const int tl = e & 255;
    const int h  = hb * H_PER + hh;
    const float* qrow = qk + ((size_t)b * S_LEN + tile * T_TILE + tl) * D_DIM;
    double dot = 0.0;
#pragma unroll 8
    for (int f = 0; f < D_DIM; ++f)
      dot = fma((double)qrow[f], (double)rot[(size_t)f * 512 + h * 64 + lane], dot);
    double vp = dot, vn = -dot;
    int ip = lane, in_ = 64 + lane;
#pragma unroll
    for (int m = 1; m < 64; m <<= 1) {
      const double ovp = __shfl_xor(vp, m);
      const int   oip = __shfl_xor(ip, m);
      if (ovp > vp || (ovp == vp && oip < ip)) { vp = ovp; ip = oip; }
      const double ovn = __shfl_xor(vn, m);
      const int   oin = __shfl_xor(in_, m);
      if (ovn > vn || (ovn == vn && oin < in_)) { vn = ovn; in_ = oin; }
    }
    if (lane == 0) {
      const int bucket = (vp >= vn) ? ip : in_;
      out[OUT0_ELEMS + ((size_t)(b * N_HASH + h)) * S_LEN + tile * T_TILE + tl] =
          (float)(bucket + h * N_BUCK);
    }
  }
}

extern "C" void kernel_launch(void* const* d_in, const int* in_sizes, int n_in,
                              void* d_out, int out_size, void* d_ws, size_t ws_size,
                              hipStream_t stream) {
  const float* qk  = (const float*)d_in[0];
  const float* v   = (const float*)d_in[1];
  const float* rot = (const float*)d_in[2];
  float* out = (float*)d_out;

  dim3 grid(S_LEN / T_TILE, N_HASH / H_PER, BATCH);
  lsh_mfma_kernel<<<grid, THREADS, 0, stream>>>(qk, v, rot, out);
}